// Round 11
// baseline (704.026 us; speedup 1.0000x reference)
//
#include <hip/hip_runtime.h>
#include <hip/hip_bf16.h>

#define GG 2048
#define PP 10
#define HHC 128
#define NSTEP 25
#define NROW (GG*PP)      // 20480
#define ASTR 216          // lstm Ahi stride (bf16)
#define LSTR 136          // lstm Alo stride
#define LROWS 80          // rows per lstm block
#define LB 768            // lstm threads per block
#define GPB 4             // graphs per graphconv block
#define ADJS 40           // adjacency row stride (u16)
#define HS 72             // hrow/hT stride (u16)
#define AFS 200           // Afeat stride (u16)

typedef __attribute__((ext_vector_type(8))) short bf16x8;
typedef __attribute__((ext_vector_type(16))) float f32x16;
typedef unsigned short ushort_t;

__device__ __forceinline__ float sigf(float x){ return 1.f/(1.f+__expf(-x)); }
__device__ __forceinline__ float tanhf_(float x){ return 2.f/(1.f+__expf(-2.f*x)) - 1.f; }

__device__ __forceinline__ ushort_t f2b(float f){
  union{float f; unsigned u;} v; v.f=f;
  unsigned r = v.u + 0x7FFFu + ((v.u>>16)&1u);
  return (ushort_t)(r>>16);
}
__device__ __forceinline__ float b2f(ushort_t u){
  union{unsigned u; float f;} v; v.u = ((unsigned)u)<<16; return v.f;
}
__device__ __forceinline__ void st4(ushort_t* dst, float a, float b, float c, float d){
  ushort4 u; u.x=f2b(a); u.y=f2b(b); u.z=f2b(c); u.w=f2b(d);
  *(ushort4*)dst = u;
}

#define MFMA32(A,B,C) __builtin_amdgcn_mfma_f32_32x32x16_bf16(A,B,C,0,0,0)
#define BC8(u) __builtin_bit_cast(bf16x8, u)

// ---------------------------------------------------------------------------
// LSTM weight pack (proven, unchanged).
// ---------------------------------------------------------------------------
__global__ __launch_bounds__(256) void prep_pack(
    const float* __restrict__ wih, const float* __restrict__ whh,
    const float* __restrict__ bih, const float* __restrict__ bhh,
    ushort_t* __restrict__ bph, ushort_t* __restrict__ bpl)
{
  int id = blockIdx.x*256 + threadIdx.x;   // 25*13*16*64 = 332800
  int lane = id & 63;
  int r  = id >> 6;
  int nt = r & 15;
  int r2 = r >> 4;
  int kstep = r2 % 13;
  int s     = r2 / 13;
  int col = nt*32 + (lane&31);
  int k0  = kstep*16 + ((lane>>5)<<3);
  ushort_t hi[8], lo[8];
  #pragma unroll
  for (int j=0;j<8;j++){
    int k = k0+j;
    float w = 0.f;
    if (k < 64)       w = wih[((size_t)s*512+col)*66 + k];
    else if (k < 192) w = whh[((size_t)s*512+col)*128 + (k-64)];
    else if (k < 194) w = wih[((size_t)s*512+col)*66 + 64 + (k-192)];
    else if (k == 194) w = bih[(size_t)s*512+col] + bhh[(size_t)s*512+col];
    ushort_t h_ = f2b(w);
    hi[j] = h_;
    lo[j] = f2b(w - b2f(h_));
  }
  uint4 uh, ul;
  uh.x = hi[0] | ((unsigned)hi[1]<<16); uh.y = hi[2] | ((unsigned)hi[3]<<16);
  uh.z = hi[4] | ((unsigned)hi[5]<<16); uh.w = hi[6] | ((unsigned)hi[7]<<16);
  ul.x = lo[0] | ((unsigned)lo[1]<<16); ul.y = lo[2] | ((unsigned)lo[3]<<16);
  ul.z = lo[4] | ((unsigned)lo[5]<<16); ul.w = lo[6] | ((unsigned)lo[7]<<16);
  *(uint4*)&bph[(size_t)id*8] = uh;
  *(uint4*)&bpl[(size_t)id*8] = ul;
}

// ---------------------------------------------------------------------------
// Graphconv weight pack (unchanged).
// ---------------------------------------------------------------------------
__global__ __launch_bounds__(256) void prep_gw(
    const float* __restrict__ wpb, const float* __restrict__ wnb,
    const float* __restrict__ wpd, const float* __restrict__ wnd,
    ushort_t* __restrict__ gw)
{
  int id = blockIdx.x*256 + threadIdx.x;   // 8192
  int lane = id & 63;
  int r = id >> 6;                          // 0..127
  int hl = r & 1, path = (r>>1)&1, slot = r>>2;
  int col = lane & 31;
  int kb = (lane>>5)*8;
  ushort_t outv[8];
  #pragma unroll
  for (int j=0;j<8;j++){
    float wv;
    if (slot < 4){
      int k = slot*16 + kb + j;
      wv = (path? wnb : wpb)[k*32 + col];
    } else {
      int sl = slot-4; int layer = sl/14, kstep = sl%14;
      int k = kstep*16 + kb + j;
      wv = (path? wnd : wpd)[((size_t)layer*224 + k)*32 + col];
    }
    ushort_t h = f2b(wv);
    outv[j] = hl ? f2b(wv - b2f(h)) : h;
  }
  uint4 u;
  u.x = outv[0]|((unsigned)outv[1]<<16); u.y = outv[2]|((unsigned)outv[3]<<16);
  u.z = outv[4]|((unsigned)outv[5]<<16); u.w = outv[6]|((unsigned)outv[7]<<16);
  *(uint4*)&gw[(size_t)id*8] = u;
}

// ---------------------------------------------------------------------------
// Operand-swapped MFMA graphconv (unchanged from round 9/10, proven ~250 us).
// ---------------------------------------------------------------------------
__global__ __launch_bounds__(256) void graphconv(
    const float* __restrict__ h0,
    const float* __restrict__ bpb, const float* __restrict__ bnb,
    const float* __restrict__ bpd, const float* __restrict__ bnd,
    const ushort_t* __restrict__ gw,
    const int* __restrict__ pos_adj, const int* __restrict__ neg_adj,
    ushort_t* __restrict__ xout)
{
  __shared__ __align__(16) ushort_t adjA[4][2][32*ADJS];
  __shared__ __align__(16) ushort_t hT[64*HS];
  __shared__ __align__(16) ushort_t hrow[64*HS];
  __shared__ __align__(16) ushort_t Afeat[64*AFS];
  __shared__ float dinv[4][64];

  const int t = threadIdx.x;
  const int lane = t & 63;
  const int w = t >> 6;
  const int pair = w >> 1;
  const int path = w & 1;
  const long g0 = (long)blockIdx.x * GPB;
  const int nrow = lane & 31;
  const int row64 = pair*32 + nrow;
  const int kof = (lane>>5)*8;
  const int fbase = 4*(lane>>5);
  const uint4* gw4 = (const uint4*)gw;

  for (int i=t; i<10240; i+=256) ((unsigned*)adjA)[i] = 0u;
  for (int i=t; i<2304; i+=256)  ((unsigned*)hT)[i]   = 0u;
  __syncthreads();

  for (int idx=t; idx<400; idx+=256){
    int g=idx/100, e=idx%100, r=e/10, c=e%10;
    if (r!=c){
      ushort_t pv = pos_adj[(g0+g)*100+e] ? (ushort_t)0x3F80 : (ushort_t)0;
      ushort_t nv = neg_adj[(g0+g)*100+e] ? (ushort_t)0x3F80 : (ushort_t)0;
      int pr=g>>1, gi=g&1;
      int rr=gi*16+r, cc=gi*16+c;
      adjA[0][pr][rr*ADJS+cc]=pv;
      adjA[1][pr][rr*ADJS+cc]=nv;
      adjA[2][pr][cc*ADJS+rr]=pv;
      adjA[3][pr][cc*ADJS+rr]=nv;
    }
  }
  if (t < 160){
    int r40=t>>2, seg=t&3;
    int g=r40/10, p=r40%10;
    int r64 = g*16 + p;
    const float* hr = h0 + ((size_t)(g0+g)*10 + p)*32 + seg*8;
    float4 v0=((const float4*)hr)[0], v1=((const float4*)hr)[1];
    float vv[8]={v0.x,v0.y,v0.z,v0.w,v1.x,v1.y,v1.z,v1.w};
    #pragma unroll
    for (int j=0;j<8;j++){
      ushort_t hi_=f2b(vv[j]);
      hrow[r64*HS + seg*8+j]      = hi_;
      hrow[r64*HS + 32 + seg*8+j] = f2b(vv[j]-b2f(hi_));
      hT[(seg*8+j)*HS + r64]      = hi_;
    }
  }
  if (t < 64){
    int g=t>>4, p=t&15;
    float rp=0,rn=0,cp=0,cn=0;
    if (p<10){
      const int* pb = pos_adj + (g0+g)*100;
      const int* nb = neg_adj + (g0+g)*100;
      for (int c=0;c<10;c++) if (c!=p){
        rp+=(float)pb[p*10+c]; rn+=(float)nb[p*10+c];
        cp+=(float)pb[c*10+p]; cn+=(float)nb[c*10+p];
      }
      rp=1.f/fmaxf(rp,1.f); rn=1.f/fmaxf(rn,1.f);
      cp=1.f/fmaxf(cp,1.f); cn=1.f/fmaxf(cn,1.f);
    }
    dinv[0][t]=rp; dinv[1][t]=rn; dinv[2][t]=cp; dinv[3][t]=cn;
  }
  __syncthreads();

  {
    f32x16 e;
    #pragma unroll
    for (int i=0;i<16;i++) e[i]=0.f;
    #pragma unroll
    for (int ks=0;ks<2;++ks){
      bf16x8 a = *(const bf16x8*)&hT[nrow*HS + pair*32 + ks*16 + kof];
      bf16x8 b = *(const bf16x8*)&adjA[path][pair][nrow*ADJS + ks*16 + kof];
      e = MFMA32(a, b, e);
    }
    float s = dinv[path][row64];
    #pragma unroll
    for (int q=0;q<4;q++)
      st4(&Afeat[row64*AFS + path*32 + fbase + 8*q],
          e[4*q]*s, e[4*q+1]*s, e[4*q+2]*s, e[4*q+3]*s);
  }
  __syncthreads();

  {
    f32x16 acc;
    #pragma unroll
    for (int i=0;i<16;i++) acc[i]=0.f;
    #pragma unroll
    for (int ks=0;ks<2;++ks){
      uint4 wh = gw4[((ks*2+path)*2+0)*64 + lane];
      uint4 wl = gw4[((ks*2+path)*2+1)*64 + lane];
      bf16x8 b = *(const bf16x8*)&Afeat[row64*AFS + path*32 + ks*16 + kof];
      acc = MFMA32(BC8(wh), b, acc);
      acc = MFMA32(BC8(wl), b, acc);
    }
    #pragma unroll
    for (int ks=0;ks<2;++ks){
      uint4 wh = gw4[(((ks+2)*2+path)*2+0)*64 + lane];
      uint4 wl = gw4[(((ks+2)*2+path)*2+1)*64 + lane];
      bf16x8 b  = *(const bf16x8*)&hrow[row64*HS + ks*16 + kof];
      bf16x8 bl = *(const bf16x8*)&hrow[row64*HS + 32 + ks*16 + kof];
      acc = MFMA32(BC8(wh), b,  acc);
      acc = MFMA32(BC8(wl), b,  acc);
      acc = MFMA32(BC8(wh), bl, acc);
    }
    const float* bs = path ? bnb : bpb;
    float v[16]; float ss = 0.f;
    #pragma unroll
    for (int i=0;i<16;i++){
      int f = fbase + (i&3) + 8*(i>>2);
      v[i] = acc[i] + bs[f];
      ss += v[i]*v[i];
    }
    ss += __shfl_xor(ss,32);
    float sc = 1.f/fmaxf(sqrtf(ss),1e-12f);
    ushort_t qv[16];
    #pragma unroll
    for (int i=0;i<16;i++) qv[i] = f2b(v[i]*sc);
    __syncthreads();
    #pragma unroll
    for (int q=0;q<4;q++)
      *(ushort4*)&hrow[row64*HS + path*32 + fbase + 8*q] =
        make_ushort4(qv[4*q],qv[4*q+1],qv[4*q+2],qv[4*q+3]);
    #pragma unroll
    for (int i=0;i<16;i++){
      int f = fbase + (i&3) + 8*(i>>2);
      hT[(path*32+f)*HS + row64] = qv[i];
    }
  }
  __syncthreads();

  #pragma unroll 1
  for (int layer=0; layer<2; ++layer){
    {
      f32x16 e0,e1,e2;
      #pragma unroll
      for (int i=0;i<16;i++){ e0[i]=0.f; e1[i]=0.f; e2[i]=0.f; }
      #pragma unroll
      for (int ks=0;ks<2;++ks){
        bf16x8 ahp = *(const bf16x8*)&hT[nrow*HS      + pair*32 + ks*16 + kof];
        bf16x8 ahn = *(const bf16x8*)&hT[(32+nrow)*HS + pair*32 + ks*16 + kof];
        bf16x8 bS  = *(const bf16x8*)&adjA[path][pair][nrow*ADJS + ks*16 + kof];
        bf16x8 bT  = *(const bf16x8*)&adjA[2+path][pair][nrow*ADJS + ks*16 + kof];
        if (path==0){
          e0 = MFMA32(ahp, bS, e0);
          e1 = MFMA32(ahn, bS, e1);
          e2 = MFMA32(ahp, bT, e2);
        } else {
          e0 = MFMA32(ahn, bS, e0);
          e1 = MFMA32(ahp, bS, e1);
          e2 = MFMA32(ahn, bT, e2);
        }
      }
      const int c0 = path? 32 : 0;
      const int c1 = path? 96 : 64;
      const int c2 = path? 160 : 128;
      float sR = dinv[path][row64];
      float sC = dinv[2+path][row64];
      #pragma unroll
      for (int q=0;q<4;q++){
        st4(&Afeat[row64*AFS + c0 + fbase + 8*q],
            e0[4*q]*sR, e0[4*q+1]*sR, e0[4*q+2]*sR, e0[4*q+3]*sR);
        st4(&Afeat[row64*AFS + c1 + fbase + 8*q],
            e1[4*q]*sR, e1[4*q+1]*sR, e1[4*q+2]*sR, e1[4*q+3]*sR);
        st4(&Afeat[row64*AFS + c2 + fbase + 8*q],
            e2[4*q]*sC, e2[4*q+1]*sC, e2[4*q+2]*sC, e2[4*q+3]*sC);
      }
    }
    __syncthreads();

    f32x16 acc;
    #pragma unroll
    for (int i=0;i<16;i++) acc[i]=0.f;
    const int slot0 = 4 + layer*14;
    #pragma unroll
    for (int kstep=0; kstep<12; ++kstep){
      uint4 wh = gw4[(((slot0+kstep)*2+path)*2+0)*64 + lane];
      uint4 wl = gw4[(((slot0+kstep)*2+path)*2+1)*64 + lane];
      bf16x8 b = *(const bf16x8*)&Afeat[row64*AFS + kstep*16 + kof];
      acc = MFMA32(BC8(wh), b, acc);
      acc = MFMA32(BC8(wl), b, acc);
    }
    #pragma unroll
    for (int ks=0;ks<2;++ks){
      uint4 wh = gw4[(((slot0+12+ks)*2+path)*2+0)*64 + lane];
      uint4 wl = gw4[(((slot0+12+ks)*2+path)*2+1)*64 + lane];
      bf16x8 b = *(const bf16x8*)&hrow[row64*HS + path*32 + ks*16 + kof];
      acc = MFMA32(BC8(wh), b, acc);
      acc = MFMA32(BC8(wl), b, acc);
    }
    const float* bs = (path ? bnd : bpd) + layer*32;
    float v[16]; float ss = 0.f;
    #pragma unroll
    for (int i=0;i<16;i++){
      int f = fbase + (i&3) + 8*(i>>2);
      v[i] = acc[i] + bs[f];
      ss += v[i]*v[i];
    }
    ss += __shfl_xor(ss,32);
    float sc = 1.f/fmaxf(sqrtf(ss),1e-12f);
    ushort_t qv[16];
    #pragma unroll
    for (int i=0;i<16;i++) qv[i] = f2b(v[i]*sc);

    if (layer==0){
      __syncthreads();
      #pragma unroll
      for (int q=0;q<4;q++)
        *(ushort4*)&hrow[row64*HS + path*32 + fbase + 8*q] =
          make_ushort4(qv[4*q],qv[4*q+1],qv[4*q+2],qv[4*q+3]);
      #pragma unroll
      for (int i=0;i<16;i++){
        int f = fbase + (i&3) + 8*(i>>2);
        hT[(path*32+f)*HS + row64] = qv[i];
      }
      __syncthreads();
    } else {
      int p_ = row64 & 15;
      if (p_ < 10){
        long gid = g0 + (row64>>4);
        size_t base = ((size_t)(gid%25)*NROW + (size_t)(gid/25)*10 + p_)*64 + path*32;
        #pragma unroll
        for (int q=0;q<4;q++)
          *(ushort4*)&xout[base + fbase + 8*q] =
            make_ushort4(qv[4*q],qv[4*q+1],qv[4*q+2],qv[4*q+3]);
      }
    }
  }
}

// ---------------------------------------------------------------------------
// Persistent MFMA LSTM v5: B fragments loaded global->VGPR with 2-kstep-deep
// register prefetch (ping-pong pf0/pf1; end-of-step swap since 13 is odd).
// kstep loop is LDS-READ-ONLY -> zero in-loop barriers (wave drift harmless).
// Only 2 barriers/step: B1 (reads done, before hx/x LDS writes), B2 (writes
// visible). Bh LDS buffers deleted (-32 KB -> 67.6 KB LDS). x staged T14-style
// (global load at step start into regs, LDS write after B1).
// ---------------------------------------------------------------------------
__global__ __launch_bounds__(LB,3) void lstm_persist(
    const ushort_t* __restrict__ xbuf, const ushort_t* __restrict__ bph,
    const float* __restrict__ hx0, const float* __restrict__ cx0,
    const float* __restrict__ ai, float* __restrict__ outp)
{
  __shared__ __align__(16) ushort_t Ahi[96*ASTR];   // 41.5 KB
  __shared__ __align__(16) ushort_t Alo[96*LSTR];   // 26.1 KB

  const int t = threadIdx.x;
  const int lane = t & 63;
  const int w = t >> 6;
  const int mt = w >> 2;
  const int ng = w & 3;
  const long rbase = (long)blockIdx.x * LROWS;
  const int c = ng*32 + (lane&31);
  const int kof = (lane>>5)*8;
  const int arow = mt*32 + (lane&31);

  for (int i=t; i<96*ASTR/2; i+=LB) ((unsigned*)Ahi)[i] = 0u;
  for (int i=t; i<96*LSTR/2; i+=LB) ((unsigned*)Alo)[i] = 0u;
  __syncthreads();
  if (t < LROWS){
    Ahi[t*ASTR+194] = 0x3F80;
    long R = rbase + t; int g=(int)(R/10), p=(int)(R%10);
    const float* aip = ai + (((size_t)g*5+0)*10+p)*2;
    Ahi[t*ASTR+192]=f2b(aip[0]); Ahi[t*ASTR+193]=f2b(aip[1]);
  }
  if (t < 640){
    int row=t>>3, c0=(t&7)*8;
    *(uint4*)&Ahi[row*ASTR+c0] = *(const uint4*)&xbuf[((size_t)rbase+row)*64 + c0];
  }
  float cxr[16];
  #pragma unroll
  for (int i=0;i<16;i++){
    int rof=(i&3)+8*(i>>2)+4*(lane>>5);
    int lr2=mt*32+rof;
    if (lr2 < LROWS){
      long R=rbase+lr2;
      float h0v = hx0[(size_t)R*HHC+c];
      ushort_t hh=f2b(h0v);
      Ahi[lr2*ASTR+64+c]=hh;
      Alo[lr2*LSTR+c]=f2b(h0v-b2f(hh));
      cxr[i]=cx0[(size_t)R*HHC+c];
    } else cxr[i]=0.f;
  }

  // B prefetch prologue: frag m resides at bph4 + m*1024 (uint4 units);
  // wave ng needs nt = {ng, ng+4, ng+8, ng+12}.
  const uint4* bph4 = (const uint4*)bph;
  uint4 pf0[4], pf1[4];
  {
    const uint4* p0 = bph4 + lane;
    pf0[0]=p0[ng*64]; pf0[1]=p0[(ng+4)*64]; pf0[2]=p0[(ng+8)*64]; pf0[3]=p0[(ng+12)*64];
    const uint4* p1 = bph4 + 1024 + lane;
    pf1[0]=p1[ng*64]; pf1[1]=p1[(ng+4)*64]; pf1[2]=p1[(ng+8)*64]; pf1[3]=p1[(ng+12)*64];
  }
  __syncthreads();

  #pragma unroll 1
  for (int s=0; s<NSTEP; ++s){
    f32x16 acc0, acc1, acc2, acc3;
    #pragma unroll
    for (int i=0;i<16;i++){ acc0[i]=0.f; acc1[i]=0.f; acc2[i]=0.f; acc3[i]=0.f; }

    // T14: issue next step's x load now, write to LDS after B1
    uint4 xh;
    const bool xload = (s < NSTEP-1) && (t < 640);
    if (xload){
      int row=t>>3, c0=(t&7)*8;
      xh = *(const uint4*)&xbuf[((size_t)(s+1)*NROW + rbase + row)*64 + c0];
    }

    #pragma unroll
    for (int k=0; k<13; ++k){
      uint4 b0,b1,b2,b3;
      if ((k&1)==0){ b0=pf0[0]; b1=pf0[1]; b2=pf0[2]; b3=pf0[3]; }
      else         { b0=pf1[0]; b1=pf1[1]; b2=pf1[2]; b3=pf1[3]; }
      bf16x8 af = *(const bf16x8*)&Ahi[arow*ASTR + k*16 + kof];
      __builtin_amdgcn_s_setprio(1);
      acc0 = MFMA32(af, BC8(b0), acc0);
      acc1 = MFMA32(af, BC8(b1), acc1);
      acc2 = MFMA32(af, BC8(b2), acc2);
      acc3 = MFMA32(af, BC8(b3), acc3);
      if (k>=4 && k<12){
        bf16x8 al = *(const bf16x8*)&Alo[arow*LSTR + (k-4)*16 + kof];
        acc0 = MFMA32(al, BC8(b0), acc0);
        acc1 = MFMA32(al, BC8(b1), acc1);
        acc2 = MFMA32(al, BC8(b2), acc2);
        acc3 = MFMA32(al, BC8(b3), acc3);
      }
      __builtin_amdgcn_s_setprio(0);
      // reload the just-consumed slot with frag m+2 (2-deep pipeline)
      long m2 = (long)s*13 + k + 2;
      if (m2 < (long)NSTEP*13){
        const uint4* p = bph4 + (size_t)m2*1024 + lane;
        if ((k&1)==0){
          pf0[0]=p[ng*64]; pf0[1]=p[(ng+4)*64];
          pf0[2]=p[(ng+8)*64]; pf0[3]=p[(ng+12)*64];
        } else {
          pf1[0]=p[ng*64]; pf1[1]=p[(ng+4)*64];
          pf1[2]=p[(ng+8)*64]; pf1[3]=p[(ng+12)*64];
        }
      }
    }
    __syncthreads();   // B1: all waves' Ahi/Alo reads of this step complete

    // cell update (hx hi/lo LDS writes, or final output)
    #pragma unroll
    for (int i=0;i<16;i++){
      int rof=(i&3)+8*(i>>2)+4*(lane>>5);
      int lr2=mt*32+rof;
      float ig=sigf(acc0[i]), fg=sigf(acc1[i]);
      float gg=tanhf_(acc2[i]), og=sigf(acc3[i]);
      float cn = fg*cxr[i] + ig*gg;
      cxr[i]=cn;
      float h = og*tanhf_(cn);
      if (lr2 < LROWS){
        long R=rbase+lr2;
        if (s==NSTEP-1){
          outp[(size_t)R*HHC+c]=h;
        } else {
          ushort_t hh=f2b(h);
          Ahi[lr2*ASTR+64+c]=hh;
          Alo[lr2*LSTR+c]=f2b(h-b2f(hh));
        }
      }
    }
    if (s < NSTEP-1){
      if (xload){
        int row=t>>3, c0=(t&7)*8;
        *(uint4*)&Ahi[row*ASTR + c0] = xh;
      }
      if ((((s+1)%5)==0) && t<LROWS){
        long R=rbase+t; int g=(int)(R/10), p=(int)(R%10);
        const float* aip = ai + (((size_t)g*5+(s+1)/5)*10+p)*2;
        Ahi[t*ASTR+192]=f2b(aip[0]);
        Ahi[t*ASTR+193]=f2b(aip[1]);
      }
      __syncthreads();   // B2: writes visible before next step's reads
      // 13 odd -> slot parity flips each step: swap pf0 <-> pf1
      #pragma unroll
      for (int j=0;j<4;j++){ uint4 tmp=pf0[j]; pf0[j]=pf1[j]; pf1[j]=tmp; }
    }
  }
}

// ---------------------------------------------------------------------------
extern "C" void kernel_launch(void* const* d_in, const int* in_sizes, int n_in,
                              void* d_out, int out_size, void* d_ws, size_t ws_size,
                              hipStream_t stream)
{
  const float* h0  = (const float*)d_in[0];
  const float* ai  = (const float*)d_in[1];
  const float* wpb = (const float*)d_in[2];
  const float* bpb = (const float*)d_in[3];
  const float* wnb = (const float*)d_in[4];
  const float* bnb = (const float*)d_in[5];
  const float* wpd = (const float*)d_in[6];
  const float* bpd = (const float*)d_in[7];
  const float* wnd = (const float*)d_in[8];
  const float* bnd = (const float*)d_in[9];
  const float* wih = (const float*)d_in[10];
  const float* whh = (const float*)d_in[11];
  const float* bih = (const float*)d_in[12];
  const float* bhh = (const float*)d_in[13];
  const float* hx0 = (const float*)d_in[14];
  const float* cx0 = (const float*)d_in[15];
  const int* padj  = (const int*)d_in[16];
  const int* nadj  = (const int*)d_in[17];
  float* out = (float*)d_out;

  ushort_t* xbuf16 = (ushort_t*)d_ws;                        // 25*20480*64 u16
  ushort_t* bph = xbuf16 + (size_t)NSTEP*NROW*64;            // 2,662,400 u16
  ushort_t* bpl = bph + (size_t)NSTEP*13*16*64*8;            // 2,662,400 u16 (unused by lstm)
  ushort_t* gw  = bpl + (size_t)NSTEP*13*16*64*8;            // 65,536 u16

  prep_pack<<<1300,256,0,stream>>>(wih,whh,bih,bhh,bph,bpl);
  prep_gw<<<32,256,0,stream>>>(wpb,wnb,wpd,wnd,gw);
  graphconv<<<12800,256,0,stream>>>(h0,bpb,bnb,bpd,bnd,gw,padj,nadj,xbuf16);
  lstm_persist<<<256,LB,0,stream>>>(xbuf16,bph,hx0,cx0,ai,out);
}

// Round 12
// 692.237 us; speedup vs baseline: 1.0170x; 1.0170x over previous
//
#include <hip/hip_runtime.h>
#include <hip/hip_bf16.h>

#define GG 2048
#define PP 10
#define HHC 128
#define NSTEP 25
#define NROW (GG*PP)      // 20480
#define ASTR 216          // lstm Ahi stride (bf16)
#define LSTR 136          // lstm Alo stride
#define LROWS 80          // rows per lstm block
#define LB 768            // lstm threads per block
#define GPB 4             // graphs per graphconv block
#define ADJS 40           // adjacency row stride (u16)
#define HS 72             // hrow/hT stride (u16)
#define AFS 200           // Afeat stride (u16)

typedef __attribute__((ext_vector_type(8))) short bf16x8;
typedef __attribute__((ext_vector_type(16))) float f32x16;
typedef unsigned short ushort_t;

__device__ __forceinline__ float sigf(float x){ return 1.f/(1.f+__expf(-x)); }
__device__ __forceinline__ float tanhf_(float x){ return 2.f/(1.f+__expf(-2.f*x)) - 1.f; }

__device__ __forceinline__ ushort_t f2b(float f){
  union{float f; unsigned u;} v; v.f=f;
  unsigned r = v.u + 0x7FFFu + ((v.u>>16)&1u);
  return (ushort_t)(r>>16);
}
__device__ __forceinline__ float b2f(ushort_t u){
  union{unsigned u; float f;} v; v.u = ((unsigned)u)<<16; return v.f;
}
__device__ __forceinline__ void st4(ushort_t* dst, float a, float b, float c, float d){
  ushort4 u; u.x=f2b(a); u.y=f2b(b); u.z=f2b(c); u.w=f2b(d);
  *(ushort4*)dst = u;
}

#define MFMA32(A,B,C) __builtin_amdgcn_mfma_f32_32x32x16_bf16(A,B,C,0,0,0)
#define BC8(u) __builtin_bit_cast(bf16x8, u)

// ---------------------------------------------------------------------------
// LSTM weight pack (proven, unchanged).
// ---------------------------------------------------------------------------
__global__ __launch_bounds__(256) void prep_pack(
    const float* __restrict__ wih, const float* __restrict__ whh,
    const float* __restrict__ bih, const float* __restrict__ bhh,
    ushort_t* __restrict__ bph, ushort_t* __restrict__ bpl)
{
  int id = blockIdx.x*256 + threadIdx.x;   // 25*13*16*64 = 332800
  int lane = id & 63;
  int r  = id >> 6;
  int nt = r & 15;
  int r2 = r >> 4;
  int kstep = r2 % 13;
  int s     = r2 / 13;
  int col = nt*32 + (lane&31);
  int k0  = kstep*16 + ((lane>>5)<<3);
  ushort_t hi[8], lo[8];
  #pragma unroll
  for (int j=0;j<8;j++){
    int k = k0+j;
    float w = 0.f;
    if (k < 64)       w = wih[((size_t)s*512+col)*66 + k];
    else if (k < 192) w = whh[((size_t)s*512+col)*128 + (k-64)];
    else if (k < 194) w = wih[((size_t)s*512+col)*66 + 64 + (k-192)];
    else if (k == 194) w = bih[(size_t)s*512+col] + bhh[(size_t)s*512+col];
    ushort_t h_ = f2b(w);
    hi[j] = h_;
    lo[j] = f2b(w - b2f(h_));
  }
  uint4 uh, ul;
  uh.x = hi[0] | ((unsigned)hi[1]<<16); uh.y = hi[2] | ((unsigned)hi[3]<<16);
  uh.z = hi[4] | ((unsigned)hi[5]<<16); uh.w = hi[6] | ((unsigned)hi[7]<<16);
  ul.x = lo[0] | ((unsigned)lo[1]<<16); ul.y = lo[2] | ((unsigned)lo[3]<<16);
  ul.z = lo[4] | ((unsigned)lo[5]<<16); ul.w = lo[6] | ((unsigned)lo[7]<<16);
  *(uint4*)&bph[(size_t)id*8] = uh;
  *(uint4*)&bpl[(size_t)id*8] = ul;
}

// ---------------------------------------------------------------------------
// Graphconv weight pack (unchanged).
// ---------------------------------------------------------------------------
__global__ __launch_bounds__(256) void prep_gw(
    const float* __restrict__ wpb, const float* __restrict__ wnb,
    const float* __restrict__ wpd, const float* __restrict__ wnd,
    ushort_t* __restrict__ gw)
{
  int id = blockIdx.x*256 + threadIdx.x;   // 8192
  int lane = id & 63;
  int r = id >> 6;                          // 0..127
  int hl = r & 1, path = (r>>1)&1, slot = r>>2;
  int col = lane & 31;
  int kb = (lane>>5)*8;
  ushort_t outv[8];
  #pragma unroll
  for (int j=0;j<8;j++){
    float wv;
    if (slot < 4){
      int k = slot*16 + kb + j;
      wv = (path? wnb : wpb)[k*32 + col];
    } else {
      int sl = slot-4; int layer = sl/14, kstep = sl%14;
      int k = kstep*16 + kb + j;
      wv = (path? wnd : wpd)[((size_t)layer*224 + k)*32 + col];
    }
    ushort_t h = f2b(wv);
    outv[j] = hl ? f2b(wv - b2f(h)) : h;
  }
  uint4 u;
  u.x = outv[0]|((unsigned)outv[1]<<16); u.y = outv[2]|((unsigned)outv[3]<<16);
  u.z = outv[4]|((unsigned)outv[5]<<16); u.w = outv[6]|((unsigned)outv[7]<<16);
  *(uint4*)&gw[(size_t)id*8] = u;
}

// ---------------------------------------------------------------------------
// Operand-swapped MFMA graphconv (unchanged from round 9/10, proven ~250 us).
// ---------------------------------------------------------------------------
__global__ __launch_bounds__(256) void graphconv(
    const float* __restrict__ h0,
    const float* __restrict__ bpb, const float* __restrict__ bnb,
    const float* __restrict__ bpd, const float* __restrict__ bnd,
    const ushort_t* __restrict__ gw,
    const int* __restrict__ pos_adj, const int* __restrict__ neg_adj,
    ushort_t* __restrict__ xout)
{
  __shared__ __align__(16) ushort_t adjA[4][2][32*ADJS];
  __shared__ __align__(16) ushort_t hT[64*HS];
  __shared__ __align__(16) ushort_t hrow[64*HS];
  __shared__ __align__(16) ushort_t Afeat[64*AFS];
  __shared__ float dinv[4][64];

  const int t = threadIdx.x;
  const int lane = t & 63;
  const int w = t >> 6;
  const int pair = w >> 1;
  const int path = w & 1;
  const long g0 = (long)blockIdx.x * GPB;
  const int nrow = lane & 31;
  const int row64 = pair*32 + nrow;
  const int kof = (lane>>5)*8;
  const int fbase = 4*(lane>>5);
  const uint4* gw4 = (const uint4*)gw;

  for (int i=t; i<10240; i+=256) ((unsigned*)adjA)[i] = 0u;
  for (int i=t; i<2304; i+=256)  ((unsigned*)hT)[i]   = 0u;
  __syncthreads();

  for (int idx=t; idx<400; idx+=256){
    int g=idx/100, e=idx%100, r=e/10, c=e%10;
    if (r!=c){
      ushort_t pv = pos_adj[(g0+g)*100+e] ? (ushort_t)0x3F80 : (ushort_t)0;
      ushort_t nv = neg_adj[(g0+g)*100+e] ? (ushort_t)0x3F80 : (ushort_t)0;
      int pr=g>>1, gi=g&1;
      int rr=gi*16+r, cc=gi*16+c;
      adjA[0][pr][rr*ADJS+cc]=pv;
      adjA[1][pr][rr*ADJS+cc]=nv;
      adjA[2][pr][cc*ADJS+rr]=pv;
      adjA[3][pr][cc*ADJS+rr]=nv;
    }
  }
  if (t < 160){
    int r40=t>>2, seg=t&3;
    int g=r40/10, p=r40%10;
    int r64 = g*16 + p;
    const float* hr = h0 + ((size_t)(g0+g)*10 + p)*32 + seg*8;
    float4 v0=((const float4*)hr)[0], v1=((const float4*)hr)[1];
    float vv[8]={v0.x,v0.y,v0.z,v0.w,v1.x,v1.y,v1.z,v1.w};
    #pragma unroll
    for (int j=0;j<8;j++){
      ushort_t hi_=f2b(vv[j]);
      hrow[r64*HS + seg*8+j]      = hi_;
      hrow[r64*HS + 32 + seg*8+j] = f2b(vv[j]-b2f(hi_));
      hT[(seg*8+j)*HS + r64]      = hi_;
    }
  }
  if (t < 64){
    int g=t>>4, p=t&15;
    float rp=0,rn=0,cp=0,cn=0;
    if (p<10){
      const int* pb = pos_adj + (g0+g)*100;
      const int* nb = neg_adj + (g0+g)*100;
      for (int c=0;c<10;c++) if (c!=p){
        rp+=(float)pb[p*10+c]; rn+=(float)nb[p*10+c];
        cp+=(float)pb[c*10+p]; cn+=(float)nb[c*10+p];
      }
      rp=1.f/fmaxf(rp,1.f); rn=1.f/fmaxf(rn,1.f);
      cp=1.f/fmaxf(cp,1.f); cn=1.f/fmaxf(cn,1.f);
    }
    dinv[0][t]=rp; dinv[1][t]=rn; dinv[2][t]=cp; dinv[3][t]=cn;
  }
  __syncthreads();

  {
    f32x16 e;
    #pragma unroll
    for (int i=0;i<16;i++) e[i]=0.f;
    #pragma unroll
    for (int ks=0;ks<2;++ks){
      bf16x8 a = *(const bf16x8*)&hT[nrow*HS + pair*32 + ks*16 + kof];
      bf16x8 b = *(const bf16x8*)&adjA[path][pair][nrow*ADJS + ks*16 + kof];
      e = MFMA32(a, b, e);
    }
    float s = dinv[path][row64];
    #pragma unroll
    for (int q=0;q<4;q++)
      st4(&Afeat[row64*AFS + path*32 + fbase + 8*q],
          e[4*q]*s, e[4*q+1]*s, e[4*q+2]*s, e[4*q+3]*s);
  }
  __syncthreads();

  {
    f32x16 acc;
    #pragma unroll
    for (int i=0;i<16;i++) acc[i]=0.f;
    #pragma unroll
    for (int ks=0;ks<2;++ks){
      uint4 wh = gw4[((ks*2+path)*2+0)*64 + lane];
      uint4 wl = gw4[((ks*2+path)*2+1)*64 + lane];
      bf16x8 b = *(const bf16x8*)&Afeat[row64*AFS + path*32 + ks*16 + kof];
      acc = MFMA32(BC8(wh), b, acc);
      acc = MFMA32(BC8(wl), b, acc);
    }
    #pragma unroll
    for (int ks=0;ks<2;++ks){
      uint4 wh = gw4[(((ks+2)*2+path)*2+0)*64 + lane];
      uint4 wl = gw4[(((ks+2)*2+path)*2+1)*64 + lane];
      bf16x8 b  = *(const bf16x8*)&hrow[row64*HS + ks*16 + kof];
      bf16x8 bl = *(const bf16x8*)&hrow[row64*HS + 32 + ks*16 + kof];
      acc = MFMA32(BC8(wh), b,  acc);
      acc = MFMA32(BC8(wl), b,  acc);
      acc = MFMA32(BC8(wh), bl, acc);
    }
    const float* bs = path ? bnb : bpb;
    float v[16]; float ss = 0.f;
    #pragma unroll
    for (int i=0;i<16;i++){
      int f = fbase + (i&3) + 8*(i>>2);
      v[i] = acc[i] + bs[f];
      ss += v[i]*v[i];
    }
    ss += __shfl_xor(ss,32);
    float sc = 1.f/fmaxf(sqrtf(ss),1e-12f);
    ushort_t qv[16];
    #pragma unroll
    for (int i=0;i<16;i++) qv[i] = f2b(v[i]*sc);
    __syncthreads();
    #pragma unroll
    for (int q=0;q<4;q++)
      *(ushort4*)&hrow[row64*HS + path*32 + fbase + 8*q] =
        make_ushort4(qv[4*q],qv[4*q+1],qv[4*q+2],qv[4*q+3]);
    #pragma unroll
    for (int i=0;i<16;i++){
      int f = fbase + (i&3) + 8*(i>>2);
      hT[(path*32+f)*HS + row64] = qv[i];
    }
  }
  __syncthreads();

  #pragma unroll 1
  for (int layer=0; layer<2; ++layer){
    {
      f32x16 e0,e1,e2;
      #pragma unroll
      for (int i=0;i<16;i++){ e0[i]=0.f; e1[i]=0.f; e2[i]=0.f; }
      #pragma unroll
      for (int ks=0;ks<2;++ks){
        bf16x8 ahp = *(const bf16x8*)&hT[nrow*HS      + pair*32 + ks*16 + kof];
        bf16x8 ahn = *(const bf16x8*)&hT[(32+nrow)*HS + pair*32 + ks*16 + kof];
        bf16x8 bS  = *(const bf16x8*)&adjA[path][pair][nrow*ADJS + ks*16 + kof];
        bf16x8 bT  = *(const bf16x8*)&adjA[2+path][pair][nrow*ADJS + ks*16 + kof];
        if (path==0){
          e0 = MFMA32(ahp, bS, e0);
          e1 = MFMA32(ahn, bS, e1);
          e2 = MFMA32(ahp, bT, e2);
        } else {
          e0 = MFMA32(ahn, bS, e0);
          e1 = MFMA32(ahp, bS, e1);
          e2 = MFMA32(ahn, bT, e2);
        }
      }
      const int c0 = path? 32 : 0;
      const int c1 = path? 96 : 64;
      const int c2 = path? 160 : 128;
      float sR = dinv[path][row64];
      float sC = dinv[2+path][row64];
      #pragma unroll
      for (int q=0;q<4;q++){
        st4(&Afeat[row64*AFS + c0 + fbase + 8*q],
            e0[4*q]*sR, e0[4*q+1]*sR, e0[4*q+2]*sR, e0[4*q+3]*sR);
        st4(&Afeat[row64*AFS + c1 + fbase + 8*q],
            e1[4*q]*sR, e1[4*q+1]*sR, e1[4*q+2]*sR, e1[4*q+3]*sR);
        st4(&Afeat[row64*AFS + c2 + fbase + 8*q],
            e2[4*q]*sC, e2[4*q+1]*sC, e2[4*q+2]*sC, e2[4*q+3]*sC);
      }
    }
    __syncthreads();

    f32x16 acc;
    #pragma unroll
    for (int i=0;i<16;i++) acc[i]=0.f;
    const int slot0 = 4 + layer*14;
    #pragma unroll
    for (int kstep=0; kstep<12; ++kstep){
      uint4 wh = gw4[(((slot0+kstep)*2+path)*2+0)*64 + lane];
      uint4 wl = gw4[(((slot0+kstep)*2+path)*2+1)*64 + lane];
      bf16x8 b = *(const bf16x8*)&Afeat[row64*AFS + kstep*16 + kof];
      acc = MFMA32(BC8(wh), b, acc);
      acc = MFMA32(BC8(wl), b, acc);
    }
    #pragma unroll
    for (int ks=0;ks<2;++ks){
      uint4 wh = gw4[(((slot0+12+ks)*2+path)*2+0)*64 + lane];
      uint4 wl = gw4[(((slot0+12+ks)*2+path)*2+1)*64 + lane];
      bf16x8 b = *(const bf16x8*)&hrow[row64*HS + path*32 + ks*16 + kof];
      acc = MFMA32(BC8(wh), b, acc);
      acc = MFMA32(BC8(wl), b, acc);
    }
    const float* bs = (path ? bnd : bpd) + layer*32;
    float v[16]; float ss = 0.f;
    #pragma unroll
    for (int i=0;i<16;i++){
      int f = fbase + (i&3) + 8*(i>>2);
      v[i] = acc[i] + bs[f];
      ss += v[i]*v[i];
    }
    ss += __shfl_xor(ss,32);
    float sc = 1.f/fmaxf(sqrtf(ss),1e-12f);
    ushort_t qv[16];
    #pragma unroll
    for (int i=0;i<16;i++) qv[i] = f2b(v[i]*sc);

    if (layer==0){
      __syncthreads();
      #pragma unroll
      for (int q=0;q<4;q++)
        *(ushort4*)&hrow[row64*HS + path*32 + fbase + 8*q] =
          make_ushort4(qv[4*q],qv[4*q+1],qv[4*q+2],qv[4*q+3]);
      #pragma unroll
      for (int i=0;i<16;i++){
        int f = fbase + (i&3) + 8*(i>>2);
        hT[(path*32+f)*HS + row64] = qv[i];
      }
      __syncthreads();
    } else {
      int p_ = row64 & 15;
      if (p_ < 10){
        long gid = g0 + (row64>>4);
        size_t base = ((size_t)(gid%25)*NROW + (size_t)(gid/25)*10 + p_)*64 + path*32;
        #pragma unroll
        for (int q=0;q<4;q++)
          *(ushort4*)&xout[base + fbase + 8*q] =
            make_ushort4(qv[4*q],qv[4*q+1],qv[4*q+2],qv[4*q+3]);
      }
    }
  }
}

// ---------------------------------------------------------------------------
// Persistent MFMA LSTM v6: v4 sync structure with 2-kstep B buffers.
// Bp[2][32KB] holds kstep pairs (0,1)(2,3)...(10,11)(12); while computing
// pair p from Bp[pbuf], stage pair p+1 (global->reg before MFMAs, LDS write
// after) into Bp[pbuf^1]. Barriers: 7/step (one per pair) + 1 end-of-step.
// LDS 131.6 KB -> 1 block/CU -> VGPR cap 170 (no spill, unlike R11).
// ---------------------------------------------------------------------------
__global__ __launch_bounds__(LB,3) void lstm_persist(
    const ushort_t* __restrict__ xbuf, const ushort_t* __restrict__ bph,
    const float* __restrict__ hx0, const float* __restrict__ cx0,
    const float* __restrict__ ai, float* __restrict__ outp)
{
  __shared__ __align__(16) ushort_t Ahi[96*ASTR];   // 41.5 KB
  __shared__ __align__(16) ushort_t Alo[96*LSTR];   // 26.1 KB
  __shared__ __align__(16) ushort_t Bp[2][16384];   // 64 KB

  const int t = threadIdx.x;
  const int lane = t & 63;
  const int w = t >> 6;
  const int mt = w >> 2;
  const int ng = w & 3;
  const long rbase = (long)blockIdx.x * LROWS;
  const int c = ng*32 + (lane&31);
  const int kof = (lane>>5)*8;
  const int arow = mt*32 + (lane&31);
  const uint4* bph4 = (const uint4*)bph;

  for (int i=t; i<96*ASTR/2; i+=LB) ((unsigned*)Ahi)[i] = 0u;
  for (int i=t; i<96*LSTR/2; i+=LB) ((unsigned*)Alo)[i] = 0u;
  __syncthreads();
  if (t < LROWS){
    Ahi[t*ASTR+194] = 0x3F80;
    long R = rbase + t; int g=(int)(R/10), p=(int)(R%10);
    const float* aip = ai + (((size_t)g*5+0)*10+p)*2;
    Ahi[t*ASTR+192]=f2b(aip[0]); Ahi[t*ASTR+193]=f2b(aip[1]);
  }
  if (t < 640){
    int row=t>>3, c0=(t&7)*8;
    *(uint4*)&Ahi[row*ASTR+c0] = *(const uint4*)&xbuf[((size_t)rbase+row)*64 + c0];
  }
  float cxr[16];
  #pragma unroll
  for (int i=0;i<16;i++){
    int rof=(i&3)+8*(i>>2)+4*(lane>>5);
    int lr2=mt*32+rof;
    if (lr2 < LROWS){
      long R=rbase+lr2;
      float h0v = hx0[(size_t)R*HHC+c];
      ushort_t hh=f2b(h0v);
      Ahi[lr2*ASTR+64+c]=hh;
      Alo[lr2*LSTR+c]=f2b(h0v-b2f(hh));
      cxr[i]=cx0[(size_t)R*HHC+c];
    } else cxr[i]=0.f;
  }
  // prologue: stage pair (s=0, k=0,1) = 2048 uint4 into Bp[0]
  {
    uint4* db = (uint4*)&Bp[0][0];
    db[t]      = bph4[t];
    db[768+t]  = bph4[768+t];
    if (t<512) db[1536+t] = bph4[1536+t];
  }
  __syncthreads();

  int pbuf = 0;
  #pragma unroll 1
  for (int s=0; s<NSTEP; ++s){
    f32x16 acc0, acc1, acc2, acc3;
    #pragma unroll
    for (int i=0;i<16;i++){ acc0[i]=0.f; acc1[i]=0.f; acc2[i]=0.f; acc3[i]=0.f; }

    // T14: issue next step's x load now, write to LDS after the kp=6 barrier
    uint4 xh;
    const bool xload = (s < NSTEP-1) && (t < 640);
    if (xload){
      int row=t>>3, c0=(t&7)*8;
      xh = *(const uint4*)&xbuf[((size_t)(s+1)*NROW + rbase + row)*64 + c0];
    }

    #pragma unroll
    for (int kp=0; kp<7; ++kp){
      // -- issue next-pair global loads (hide under this pair's MFMAs) --
      int ns = s, nkp = kp+1;
      if (nkp==7){ ns = s+1; nkp = 0; }
      const int nu = (nkp==6)? 1024 : 2048;      // uint4 count of next pair
      const bool stg = (ns < NSTEP);
      uint4 s0, s1, s2;
      if (stg){
        const uint4* gb4 = bph4 + ((size_t)ns*13 + 2*nkp)*1024;
        s0 = gb4[t];
        if (768+t  < nu) s1 = gb4[768+t];
        if (1536+t < nu) s2 = gb4[1536+t];
      }
      // -- compute this pair's ksteps from Bp[pbuf] --
      const int k0 = 2*kp;
      const int ke = (kp==6)? 1 : 2;
      #pragma unroll
      for (int kk=0; kk<2; ++kk){
        if (kk < ke){
          const int k = k0 + kk;
          const ushort_t* bb = &Bp[pbuf][kk*8192];
          bf16x8 af = *(const bf16x8*)&Ahi[arow*ASTR + k*16 + kof];
          uint4 b0 = *(const uint4*)&bb[(ng   )*512 + lane*8];
          uint4 b1 = *(const uint4*)&bb[(ng+ 4)*512 + lane*8];
          uint4 b2 = *(const uint4*)&bb[(ng+ 8)*512 + lane*8];
          uint4 b3 = *(const uint4*)&bb[(ng+12)*512 + lane*8];
          __builtin_amdgcn_s_setprio(1);
          acc0 = MFMA32(af, BC8(b0), acc0);
          acc1 = MFMA32(af, BC8(b1), acc1);
          acc2 = MFMA32(af, BC8(b2), acc2);
          acc3 = MFMA32(af, BC8(b3), acc3);
          if (k>=4 && k<12){
            bf16x8 al = *(const bf16x8*)&Alo[arow*LSTR + (k-4)*16 + kof];
            acc0 = MFMA32(al, BC8(b0), acc0);
            acc1 = MFMA32(al, BC8(b1), acc1);
            acc2 = MFMA32(al, BC8(b2), acc2);
            acc3 = MFMA32(al, BC8(b3), acc3);
          }
          __builtin_amdgcn_s_setprio(0);
        }
      }
      // -- write staged pair into the other buffer --
      if (stg){
        uint4* db = (uint4*)&Bp[pbuf^1][0];
        db[t] = s0;
        if (768+t  < nu) db[768+t]  = s1;
        if (1536+t < nu) db[1536+t] = s2;
      }
      __syncthreads();
      pbuf ^= 1;
    }

    // cell update — all A/B reads of this step completed at the kp=6 barrier
    #pragma unroll
    for (int i=0;i<16;i++){
      int rof=(i&3)+8*(i>>2)+4*(lane>>5);
      int lr2=mt*32+rof;
      float ig=sigf(acc0[i]), fg=sigf(acc1[i]);
      float gg=tanhf_(acc2[i]), og=sigf(acc3[i]);
      float cn = fg*cxr[i] + ig*gg;
      cxr[i]=cn;
      float h = og*tanhf_(cn);
      if (lr2 < LROWS){
        long R=rbase+lr2;
        if (s==NSTEP-1){
          outp[(size_t)R*HHC+c]=h;
        } else {
          ushort_t hh=f2b(h);
          Ahi[lr2*ASTR+64+c]=hh;
          Alo[lr2*LSTR+c]=f2b(h-b2f(hh));
        }
      }
    }
    if (s < NSTEP-1){
      if (xload){
        int row=t>>3, c0=(t&7)*8;
        *(uint4*)&Ahi[row*ASTR + c0] = xh;
      }
      if ((((s+1)%5)==0) && t<LROWS){
        long R=rbase+t; int g=(int)(R/10), p=(int)(R%10);
        const float* aip = ai + (((size_t)g*5+(s+1)/5)*10+p)*2;
        Ahi[t*ASTR+192]=f2b(aip[0]);
        Ahi[t*ASTR+193]=f2b(aip[1]);
      }
      __syncthreads();   // hx/x/ai writes visible before next step's reads
    }
  }
}

// ---------------------------------------------------------------------------
extern "C" void kernel_launch(void* const* d_in, const int* in_sizes, int n_in,
                              void* d_out, int out_size, void* d_ws, size_t ws_size,
                              hipStream_t stream)
{
  const float* h0  = (const float*)d_in[0];
  const float* ai  = (const float*)d_in[1];
  const float* wpb = (const float*)d_in[2];
  const float* bpb = (const float*)d_in[3];
  const float* wnb = (const float*)d_in[4];
  const float* bnb = (const float*)d_in[5];
  const float* wpd = (const float*)d_in[6];
  const float* bpd = (const float*)d_in[7];
  const float* wnd = (const float*)d_in[8];
  const float* bnd = (const float*)d_in[9];
  const float* wih = (const float*)d_in[10];
  const float* whh = (const float*)d_in[11];
  const float* bih = (const float*)d_in[12];
  const float* bhh = (const float*)d_in[13];
  const float* hx0 = (const float*)d_in[14];
  const float* cx0 = (const float*)d_in[15];
  const int* padj  = (const int*)d_in[16];
  const int* nadj  = (const int*)d_in[17];
  float* out = (float*)d_out;

  ushort_t* xbuf16 = (ushort_t*)d_ws;                        // 25*20480*64 u16
  ushort_t* bph = xbuf16 + (size_t)NSTEP*NROW*64;            // 2,662,400 u16
  ushort_t* bpl = bph + (size_t)NSTEP*13*16*64*8;            // 2,662,400 u16 (unused by lstm)
  ushort_t* gw  = bpl + (size_t)NSTEP*13*16*64*8;            // 65,536 u16

  prep_pack<<<1300,256,0,stream>>>(wih,whh,bih,bhh,bph,bpl);
  prep_gw<<<32,256,0,stream>>>(wpb,wnb,wpd,wnd,gw);
  graphconv<<<12800,256,0,stream>>>(h0,bpb,bnb,bpd,bnd,gw,padj,nadj,xbuf16);
  lstm_persist<<<256,LB,0,stream>>>(xbuf16,bph,hx0,cx0,ai,out);
}

// Round 13
// 685.466 us; speedup vs baseline: 1.0271x; 1.0099x over previous
//
#include <hip/hip_runtime.h>
#include <hip/hip_bf16.h>

#define GG 2048
#define PP 10
#define HHC 128
#define NSTEP 25
#define NROW (GG*PP)      // 20480
#define ASTR 216          // lstm Ahi stride (bf16)
#define LSTR 136          // lstm Alo stride
#define LROWS 80          // rows per lstm block
#define LB 768            // lstm threads per block
#define GPB 4             // graphs per graphconv block
#define ADJS 40           // adjacency row stride (u16)
#define HS 72             // hrow/hT stride (u16)
#define AFS 200           // Afeat stride (u16)

typedef __attribute__((ext_vector_type(8))) short bf16x8;
typedef __attribute__((ext_vector_type(16))) float f32x16;
typedef unsigned short ushort_t;

__device__ __forceinline__ float sigf(float x){ return 1.f/(1.f+__expf(-x)); }
__device__ __forceinline__ float tanhf_(float x){ return 2.f/(1.f+__expf(-2.f*x)) - 1.f; }

__device__ __forceinline__ ushort_t f2b(float f){
  union{float f; unsigned u;} v; v.f=f;
  unsigned r = v.u + 0x7FFFu + ((v.u>>16)&1u);
  return (ushort_t)(r>>16);
}
__device__ __forceinline__ float b2f(ushort_t u){
  union{unsigned u; float f;} v; v.u = ((unsigned)u)<<16; return v.f;
}
__device__ __forceinline__ void st4(ushort_t* dst, float a, float b, float c, float d){
  ushort4 u; u.x=f2b(a); u.y=f2b(b); u.z=f2b(c); u.w=f2b(d);
  *(ushort4*)dst = u;
}

#define MFMA32(A,B,C) __builtin_amdgcn_mfma_f32_32x32x16_bf16(A,B,C,0,0,0)
#define BC8(u) __builtin_bit_cast(bf16x8, u)

// ---------------------------------------------------------------------------
// LSTM weight pack: hi plane only (lo plane no longer consumed anywhere).
// ---------------------------------------------------------------------------
__global__ __launch_bounds__(256) void prep_pack(
    const float* __restrict__ wih, const float* __restrict__ whh,
    const float* __restrict__ bih, const float* __restrict__ bhh,
    ushort_t* __restrict__ bph)
{
  int id = blockIdx.x*256 + threadIdx.x;   // 25*13*16*64 = 332800
  int lane = id & 63;
  int r  = id >> 6;
  int nt = r & 15;
  int r2 = r >> 4;
  int kstep = r2 % 13;
  int s     = r2 / 13;
  int col = nt*32 + (lane&31);
  int k0  = kstep*16 + ((lane>>5)<<3);
  ushort_t hi[8];
  #pragma unroll
  for (int j=0;j<8;j++){
    int k = k0+j;
    float w = 0.f;
    if (k < 64)       w = wih[((size_t)s*512+col)*66 + k];
    else if (k < 192) w = whh[((size_t)s*512+col)*128 + (k-64)];
    else if (k < 194) w = wih[((size_t)s*512+col)*66 + 64 + (k-192)];
    else if (k == 194) w = bih[(size_t)s*512+col] + bhh[(size_t)s*512+col];
    hi[j] = f2b(w);
  }
  uint4 uh;
  uh.x = hi[0] | ((unsigned)hi[1]<<16); uh.y = hi[2] | ((unsigned)hi[3]<<16);
  uh.z = hi[4] | ((unsigned)hi[5]<<16); uh.w = hi[6] | ((unsigned)hi[7]<<16);
  *(uint4*)&bph[(size_t)id*8] = uh;
}

// ---------------------------------------------------------------------------
// Graphconv weight pack (unchanged).
// ---------------------------------------------------------------------------
__global__ __launch_bounds__(256) void prep_gw(
    const float* __restrict__ wpb, const float* __restrict__ wnb,
    const float* __restrict__ wpd, const float* __restrict__ wnd,
    ushort_t* __restrict__ gw)
{
  int id = blockIdx.x*256 + threadIdx.x;   // 8192
  int lane = id & 63;
  int r = id >> 6;                          // 0..127
  int hl = r & 1, path = (r>>1)&1, slot = r>>2;
  int col = lane & 31;
  int kb = (lane>>5)*8;
  ushort_t outv[8];
  #pragma unroll
  for (int j=0;j<8;j++){
    float wv;
    if (slot < 4){
      int k = slot*16 + kb + j;
      wv = (path? wnb : wpb)[k*32 + col];
    } else {
      int sl = slot-4; int layer = sl/14, kstep = sl%14;
      int k = kstep*16 + kb + j;
      wv = (path? wnd : wpd)[((size_t)layer*224 + k)*32 + col];
    }
    ushort_t h = f2b(wv);
    outv[j] = hl ? f2b(wv - b2f(h)) : h;
  }
  uint4 u;
  u.x = outv[0]|((unsigned)outv[1]<<16); u.y = outv[2]|((unsigned)outv[3]<<16);
  u.z = outv[4]|((unsigned)outv[5]<<16); u.w = outv[6]|((unsigned)outv[7]<<16);
  *(uint4*)&gw[(size_t)id*8] = u;
}

// ---------------------------------------------------------------------------
// Operand-swapped MFMA graphconv (unchanged from round 9/10, proven ~250 us).
// ---------------------------------------------------------------------------
__global__ __launch_bounds__(256) void graphconv(
    const float* __restrict__ h0,
    const float* __restrict__ bpb, const float* __restrict__ bnb,
    const float* __restrict__ bpd, const float* __restrict__ bnd,
    const ushort_t* __restrict__ gw,
    const int* __restrict__ pos_adj, const int* __restrict__ neg_adj,
    ushort_t* __restrict__ xout)
{
  __shared__ __align__(16) ushort_t adjA[4][2][32*ADJS];
  __shared__ __align__(16) ushort_t hT[64*HS];
  __shared__ __align__(16) ushort_t hrow[64*HS];
  __shared__ __align__(16) ushort_t Afeat[64*AFS];
  __shared__ float dinv[4][64];

  const int t = threadIdx.x;
  const int lane = t & 63;
  const int w = t >> 6;
  const int pair = w >> 1;
  const int path = w & 1;
  const long g0 = (long)blockIdx.x * GPB;
  const int nrow = lane & 31;
  const int row64 = pair*32 + nrow;
  const int kof = (lane>>5)*8;
  const int fbase = 4*(lane>>5);
  const uint4* gw4 = (const uint4*)gw;

  for (int i=t; i<10240; i+=256) ((unsigned*)adjA)[i] = 0u;
  for (int i=t; i<2304; i+=256)  ((unsigned*)hT)[i]   = 0u;
  __syncthreads();

  for (int idx=t; idx<400; idx+=256){
    int g=idx/100, e=idx%100, r=e/10, c=e%10;
    if (r!=c){
      ushort_t pv = pos_adj[(g0+g)*100+e] ? (ushort_t)0x3F80 : (ushort_t)0;
      ushort_t nv = neg_adj[(g0+g)*100+e] ? (ushort_t)0x3F80 : (ushort_t)0;
      int pr=g>>1, gi=g&1;
      int rr=gi*16+r, cc=gi*16+c;
      adjA[0][pr][rr*ADJS+cc]=pv;
      adjA[1][pr][rr*ADJS+cc]=nv;
      adjA[2][pr][cc*ADJS+rr]=pv;
      adjA[3][pr][cc*ADJS+rr]=nv;
    }
  }
  if (t < 160){
    int r40=t>>2, seg=t&3;
    int g=r40/10, p=r40%10;
    int r64 = g*16 + p;
    const float* hr = h0 + ((size_t)(g0+g)*10 + p)*32 + seg*8;
    float4 v0=((const float4*)hr)[0], v1=((const float4*)hr)[1];
    float vv[8]={v0.x,v0.y,v0.z,v0.w,v1.x,v1.y,v1.z,v1.w};
    #pragma unroll
    for (int j=0;j<8;j++){
      ushort_t hi_=f2b(vv[j]);
      hrow[r64*HS + seg*8+j]      = hi_;
      hrow[r64*HS + 32 + seg*8+j] = f2b(vv[j]-b2f(hi_));
      hT[(seg*8+j)*HS + r64]      = hi_;
    }
  }
  if (t < 64){
    int g=t>>4, p=t&15;
    float rp=0,rn=0,cp=0,cn=0;
    if (p<10){
      const int* pb = pos_adj + (g0+g)*100;
      const int* nb = neg_adj + (g0+g)*100;
      for (int c=0;c<10;c++) if (c!=p){
        rp+=(float)pb[p*10+c]; rn+=(float)nb[p*10+c];
        cp+=(float)pb[c*10+p]; cn+=(float)nb[c*10+p];
      }
      rp=1.f/fmaxf(rp,1.f); rn=1.f/fmaxf(rn,1.f);
      cp=1.f/fmaxf(cp,1.f); cn=1.f/fmaxf(cn,1.f);
    }
    dinv[0][t]=rp; dinv[1][t]=rn; dinv[2][t]=cp; dinv[3][t]=cn;
  }
  __syncthreads();

  {
    f32x16 e;
    #pragma unroll
    for (int i=0;i<16;i++) e[i]=0.f;
    #pragma unroll
    for (int ks=0;ks<2;++ks){
      bf16x8 a = *(const bf16x8*)&hT[nrow*HS + pair*32 + ks*16 + kof];
      bf16x8 b = *(const bf16x8*)&adjA[path][pair][nrow*ADJS + ks*16 + kof];
      e = MFMA32(a, b, e);
    }
    float s = dinv[path][row64];
    #pragma unroll
    for (int q=0;q<4;q++)
      st4(&Afeat[row64*AFS + path*32 + fbase + 8*q],
          e[4*q]*s, e[4*q+1]*s, e[4*q+2]*s, e[4*q+3]*s);
  }
  __syncthreads();

  {
    f32x16 acc;
    #pragma unroll
    for (int i=0;i<16;i++) acc[i]=0.f;
    #pragma unroll
    for (int ks=0;ks<2;++ks){
      uint4 wh = gw4[((ks*2+path)*2+0)*64 + lane];
      uint4 wl = gw4[((ks*2+path)*2+1)*64 + lane];
      bf16x8 b = *(const bf16x8*)&Afeat[row64*AFS + path*32 + ks*16 + kof];
      acc = MFMA32(BC8(wh), b, acc);
      acc = MFMA32(BC8(wl), b, acc);
    }
    #pragma unroll
    for (int ks=0;ks<2;++ks){
      uint4 wh = gw4[(((ks+2)*2+path)*2+0)*64 + lane];
      uint4 wl = gw4[(((ks+2)*2+path)*2+1)*64 + lane];
      bf16x8 b  = *(const bf16x8*)&hrow[row64*HS + ks*16 + kof];
      bf16x8 bl = *(const bf16x8*)&hrow[row64*HS + 32 + ks*16 + kof];
      acc = MFMA32(BC8(wh), b,  acc);
      acc = MFMA32(BC8(wl), b,  acc);
      acc = MFMA32(BC8(wh), bl, acc);
    }
    const float* bs = path ? bnb : bpb;
    float v[16]; float ss = 0.f;
    #pragma unroll
    for (int i=0;i<16;i++){
      int f = fbase + (i&3) + 8*(i>>2);
      v[i] = acc[i] + bs[f];
      ss += v[i]*v[i];
    }
    ss += __shfl_xor(ss,32);
    float sc = 1.f/fmaxf(sqrtf(ss),1e-12f);
    ushort_t qv[16];
    #pragma unroll
    for (int i=0;i<16;i++) qv[i] = f2b(v[i]*sc);
    __syncthreads();
    #pragma unroll
    for (int q=0;q<4;q++)
      *(ushort4*)&hrow[row64*HS + path*32 + fbase + 8*q] =
        make_ushort4(qv[4*q],qv[4*q+1],qv[4*q+2],qv[4*q+3]);
    #pragma unroll
    for (int i=0;i<16;i++){
      int f = fbase + (i&3) + 8*(i>>2);
      hT[(path*32+f)*HS + row64] = qv[i];
    }
  }
  __syncthreads();

  #pragma unroll 1
  for (int layer=0; layer<2; ++layer){
    {
      f32x16 e0,e1,e2;
      #pragma unroll
      for (int i=0;i<16;i++){ e0[i]=0.f; e1[i]=0.f; e2[i]=0.f; }
      #pragma unroll
      for (int ks=0;ks<2;++ks){
        bf16x8 ahp = *(const bf16x8*)&hT[nrow*HS      + pair*32 + ks*16 + kof];
        bf16x8 ahn = *(const bf16x8*)&hT[(32+nrow)*HS + pair*32 + ks*16 + kof];
        bf16x8 bS  = *(const bf16x8*)&adjA[path][pair][nrow*ADJS + ks*16 + kof];
        bf16x8 bT  = *(const bf16x8*)&adjA[2+path][pair][nrow*ADJS + ks*16 + kof];
        if (path==0){
          e0 = MFMA32(ahp, bS, e0);
          e1 = MFMA32(ahn, bS, e1);
          e2 = MFMA32(ahp, bT, e2);
        } else {
          e0 = MFMA32(ahn, bS, e0);
          e1 = MFMA32(ahp, bS, e1);
          e2 = MFMA32(ahn, bT, e2);
        }
      }
      const int c0 = path? 32 : 0;
      const int c1 = path? 96 : 64;
      const int c2 = path? 160 : 128;
      float sR = dinv[path][row64];
      float sC = dinv[2+path][row64];
      #pragma unroll
      for (int q=0;q<4;q++){
        st4(&Afeat[row64*AFS + c0 + fbase + 8*q],
            e0[4*q]*sR, e0[4*q+1]*sR, e0[4*q+2]*sR, e0[4*q+3]*sR);
        st4(&Afeat[row64*AFS + c1 + fbase + 8*q],
            e1[4*q]*sR, e1[4*q+1]*sR, e1[4*q+2]*sR, e1[4*q+3]*sR);
        st4(&Afeat[row64*AFS + c2 + fbase + 8*q],
            e2[4*q]*sC, e2[4*q+1]*sC, e2[4*q+2]*sC, e2[4*q+3]*sC);
      }
    }
    __syncthreads();

    f32x16 acc;
    #pragma unroll
    for (int i=0;i<16;i++) acc[i]=0.f;
    const int slot0 = 4 + layer*14;
    #pragma unroll
    for (int kstep=0; kstep<12; ++kstep){
      uint4 wh = gw4[(((slot0+kstep)*2+path)*2+0)*64 + lane];
      uint4 wl = gw4[(((slot0+kstep)*2+path)*2+1)*64 + lane];
      bf16x8 b = *(const bf16x8*)&Afeat[row64*AFS + kstep*16 + kof];
      acc = MFMA32(BC8(wh), b, acc);
      acc = MFMA32(BC8(wl), b, acc);
    }
    #pragma unroll
    for (int ks=0;ks<2;++ks){
      uint4 wh = gw4[(((slot0+12+ks)*2+path)*2+0)*64 + lane];
      uint4 wl = gw4[(((slot0+12+ks)*2+path)*2+1)*64 + lane];
      bf16x8 b = *(const bf16x8*)&hrow[row64*HS + path*32 + ks*16 + kof];
      acc = MFMA32(BC8(wh), b, acc);
      acc = MFMA32(BC8(wl), b, acc);
    }
    const float* bs = (path ? bnd : bpd) + layer*32;
    float v[16]; float ss = 0.f;
    #pragma unroll
    for (int i=0;i<16;i++){
      int f = fbase + (i&3) + 8*(i>>2);
      v[i] = acc[i] + bs[f];
      ss += v[i]*v[i];
    }
    ss += __shfl_xor(ss,32);
    float sc = 1.f/fmaxf(sqrtf(ss),1e-12f);
    ushort_t qv[16];
    #pragma unroll
    for (int i=0;i<16;i++) qv[i] = f2b(v[i]*sc);

    if (layer==0){
      __syncthreads();
      #pragma unroll
      for (int q=0;q<4;q++)
        *(ushort4*)&hrow[row64*HS + path*32 + fbase + 8*q] =
          make_ushort4(qv[4*q],qv[4*q+1],qv[4*q+2],qv[4*q+3]);
      #pragma unroll
      for (int i=0;i<16;i++){
        int f = fbase + (i&3) + 8*(i>>2);
        hT[(path*32+f)*HS + row64] = qv[i];
      }
      __syncthreads();
    } else {
      int p_ = row64 & 15;
      if (p_ < 10){
        long gid = g0 + (row64>>4);
        size_t base = ((size_t)(gid%25)*NROW + (size_t)(gid/25)*10 + p_)*64 + path*32;
        #pragma unroll
        for (int q=0;q<4;q++)
          *(ushort4*)&xout[base + fbase + 8*q] =
            make_ushort4(qv[4*q],qv[4*q+1],qv[4*q+2],qv[4*q+3]);
      }
    }
  }
}

// ---------------------------------------------------------------------------
// Persistent MFMA LSTM v7: identical to v6 except __launch_bounds__(LB,1).
// R7-R12 all compiled at 84 VGPR (2-block/CU register target) while LDS
// forced 1 block/CU -> acc+staging spilled to scratch (WRITE_SIZE 18->35 MB).
// Bound of 1 block/CU raises the cap to ~170 VGPR: no spill.
// ---------------------------------------------------------------------------
__global__ __launch_bounds__(LB,1) void lstm_persist(
    const ushort_t* __restrict__ xbuf, const ushort_t* __restrict__ bph,
    const float* __restrict__ hx0, const float* __restrict__ cx0,
    const float* __restrict__ ai, float* __restrict__ outp)
{
  __shared__ __align__(16) ushort_t Ahi[96*ASTR];   // 41.5 KB
  __shared__ __align__(16) ushort_t Alo[96*LSTR];   // 26.1 KB
  __shared__ __align__(16) ushort_t Bp[2][16384];   // 64 KB

  const int t = threadIdx.x;
  const int lane = t & 63;
  const int w = t >> 6;
  const int mt = w >> 2;
  const int ng = w & 3;
  const long rbase = (long)blockIdx.x * LROWS;
  const int c = ng*32 + (lane&31);
  const int kof = (lane>>5)*8;
  const int arow = mt*32 + (lane&31);
  const uint4* bph4 = (const uint4*)bph;

  for (int i=t; i<96*ASTR/2; i+=LB) ((unsigned*)Ahi)[i] = 0u;
  for (int i=t; i<96*LSTR/2; i+=LB) ((unsigned*)Alo)[i] = 0u;
  __syncthreads();
  if (t < LROWS){
    Ahi[t*ASTR+194] = 0x3F80;
    long R = rbase + t; int g=(int)(R/10), p=(int)(R%10);
    const float* aip = ai + (((size_t)g*5+0)*10+p)*2;
    Ahi[t*ASTR+192]=f2b(aip[0]); Ahi[t*ASTR+193]=f2b(aip[1]);
  }
  if (t < 640){
    int row=t>>3, c0=(t&7)*8;
    *(uint4*)&Ahi[row*ASTR+c0] = *(const uint4*)&xbuf[((size_t)rbase+row)*64 + c0];
  }
  float cxr[16];
  #pragma unroll
  for (int i=0;i<16;i++){
    int rof=(i&3)+8*(i>>2)+4*(lane>>5);
    int lr2=mt*32+rof;
    if (lr2 < LROWS){
      long R=rbase+lr2;
      float h0v = hx0[(size_t)R*HHC+c];
      ushort_t hh=f2b(h0v);
      Ahi[lr2*ASTR+64+c]=hh;
      Alo[lr2*LSTR+c]=f2b(h0v-b2f(hh));
      cxr[i]=cx0[(size_t)R*HHC+c];
    } else cxr[i]=0.f;
  }
  // prologue: stage pair (s=0, k=0,1) = 2048 uint4 into Bp[0]
  {
    uint4* db = (uint4*)&Bp[0][0];
    db[t]      = bph4[t];
    db[768+t]  = bph4[768+t];
    if (t<512) db[1536+t] = bph4[1536+t];
  }
  __syncthreads();

  int pbuf = 0;
  #pragma unroll 1
  for (int s=0; s<NSTEP; ++s){
    f32x16 acc0, acc1, acc2, acc3;
    #pragma unroll
    for (int i=0;i<16;i++){ acc0[i]=0.f; acc1[i]=0.f; acc2[i]=0.f; acc3[i]=0.f; }

    // T14: issue next step's x load now, write to LDS after the kp=6 barrier
    uint4 xh;
    const bool xload = (s < NSTEP-1) && (t < 640);
    if (xload){
      int row=t>>3, c0=(t&7)*8;
      xh = *(const uint4*)&xbuf[((size_t)(s+1)*NROW + rbase + row)*64 + c0];
    }

    #pragma unroll
    for (int kp=0; kp<7; ++kp){
      // -- issue next-pair global loads (hide under this pair's MFMAs) --
      int ns = s, nkp = kp+1;
      if (nkp==7){ ns = s+1; nkp = 0; }
      const int nu = (nkp==6)? 1024 : 2048;      // uint4 count of next pair
      const bool stg = (ns < NSTEP);
      uint4 s0, s1, s2;
      if (stg){
        const uint4* gb4 = bph4 + ((size_t)ns*13 + 2*nkp)*1024;
        s0 = gb4[t];
        if (768+t  < nu) s1 = gb4[768+t];
        if (1536+t < nu) s2 = gb4[1536+t];
      }
      // -- compute this pair's ksteps from Bp[pbuf] --
      const int k0 = 2*kp;
      const int ke = (kp==6)? 1 : 2;
      #pragma unroll
      for (int kk=0; kk<2; ++kk){
        if (kk < ke){
          const int k = k0 + kk;
          const ushort_t* bb = &Bp[pbuf][kk*8192];
          bf16x8 af = *(const bf16x8*)&Ahi[arow*ASTR + k*16 + kof];
          uint4 b0 = *(const uint4*)&bb[(ng   )*512 + lane*8];
          uint4 b1 = *(const uint4*)&bb[(ng+ 4)*512 + lane*8];
          uint4 b2 = *(const uint4*)&bb[(ng+ 8)*512 + lane*8];
          uint4 b3 = *(const uint4*)&bb[(ng+12)*512 + lane*8];
          __builtin_amdgcn_s_setprio(1);
          acc0 = MFMA32(af, BC8(b0), acc0);
          acc1 = MFMA32(af, BC8(b1), acc1);
          acc2 = MFMA32(af, BC8(b2), acc2);
          acc3 = MFMA32(af, BC8(b3), acc3);
          if (k>=4 && k<12){
            bf16x8 al = *(const bf16x8*)&Alo[arow*LSTR + (k-4)*16 + kof];
            acc0 = MFMA32(al, BC8(b0), acc0);
            acc1 = MFMA32(al, BC8(b1), acc1);
            acc2 = MFMA32(al, BC8(b2), acc2);
            acc3 = MFMA32(al, BC8(b3), acc3);
          }
          __builtin_amdgcn_s_setprio(0);
        }
      }
      // -- write staged pair into the other buffer --
      if (stg){
        uint4* db = (uint4*)&Bp[pbuf^1][0];
        db[t] = s0;
        if (768+t  < nu) db[768+t]  = s1;
        if (1536+t < nu) db[1536+t] = s2;
      }
      __syncthreads();
      pbuf ^= 1;
    }

    // cell update — all A/B reads of this step completed at the kp=6 barrier
    #pragma unroll
    for (int i=0;i<16;i++){
      int rof=(i&3)+8*(i>>2)+4*(lane>>5);
      int lr2=mt*32+rof;
      float ig=sigf(acc0[i]), fg=sigf(acc1[i]);
      float gg=tanhf_(acc2[i]), og=sigf(acc3[i]);
      float cn = fg*cxr[i] + ig*gg;
      cxr[i]=cn;
      float h = og*tanhf_(cn);
      if (lr2 < LROWS){
        long R=rbase+lr2;
        if (s==NSTEP-1){
          outp[(size_t)R*HHC+c]=h;
        } else {
          ushort_t hh=f2b(h);
          Ahi[lr2*ASTR+64+c]=hh;
          Alo[lr2*LSTR+c]=f2b(h-b2f(hh));
        }
      }
    }
    if (s < NSTEP-1){
      if (xload){
        int row=t>>3, c0=(t&7)*8;
        *(uint4*)&Ahi[row*ASTR + c0] = xh;
      }
      if ((((s+1)%5)==0) && t<LROWS){
        long R=rbase+t; int g=(int)(R/10), p=(int)(R%10);
        const float* aip = ai + (((size_t)g*5+(s+1)/5)*10+p)*2;
        Ahi[t*ASTR+192]=f2b(aip[0]);
        Ahi[t*ASTR+193]=f2b(aip[1]);
      }
      __syncthreads();   // hx/x/ai writes visible before next step's reads
    }
  }
}

// ---------------------------------------------------------------------------
extern "C" void kernel_launch(void* const* d_in, const int* in_sizes, int n_in,
                              void* d_out, int out_size, void* d_ws, size_t ws_size,
                              hipStream_t stream)
{
  const float* h0  = (const float*)d_in[0];
  const float* ai  = (const float*)d_in[1];
  const float* wpb = (const float*)d_in[2];
  const float* bpb = (const float*)d_in[3];
  const float* wnb = (const float*)d_in[4];
  const float* bnb = (const float*)d_in[5];
  const float* wpd = (const float*)d_in[6];
  const float* bpd = (const float*)d_in[7];
  const float* wnd = (const float*)d_in[8];
  const float* bnd = (const float*)d_in[9];
  const float* wih = (const float*)d_in[10];
  const float* whh = (const float*)d_in[11];
  const float* bih = (const float*)d_in[12];
  const float* bhh = (const float*)d_in[13];
  const float* hx0 = (const float*)d_in[14];
  const float* cx0 = (const float*)d_in[15];
  const int* padj  = (const int*)d_in[16];
  const int* nadj  = (const int*)d_in[17];
  float* out = (float*)d_out;

  ushort_t* xbuf16 = (ushort_t*)d_ws;                        // 25*20480*64 u16
  ushort_t* bph = xbuf16 + (size_t)NSTEP*NROW*64;            // 2,662,400 u16
  ushort_t* bpl = bph + (size_t)NSTEP*13*16*64*8;            // (reserved, unused)
  ushort_t* gw  = bpl + (size_t)NSTEP*13*16*64*8;            // 65,536 u16

  prep_pack<<<1300,256,0,stream>>>(wih,whh,bih,bhh,bph);
  prep_gw<<<32,256,0,stream>>>(wpb,wnb,wpd,wnd,gw);
  graphconv<<<12800,256,0,stream>>>(h0,bpb,bnb,bpd,bnd,gw,padj,nadj,xbuf16);
  lstm_persist<<<256,LB,0,stream>>>(xbuf16,bph,hx0,cx0,ai,out);
}